// Round 4
// baseline (836.703 us; speedup 1.0000x reference)
//
#include <hip/hip_runtime.h>

// Problem constants (B=16, P=128, D=256, N=256)
#define B_SZ 16
#define P_SZ 128
#define D_CH 256
#define N_F  256
#define ROWS_TOTAL (B_SZ * P_SZ)   // 2048 (b,p) rows per channel d

// Native clang vector type — required by __builtin_nontemporal_load/store
// (HIP's float4 is a class and is rejected by the builtin).
typedef float f32x4 __attribute__((ext_vector_type(4)));

// Algebraic simplification: since perm[d,:] is a permutation,
//   sum_k x[b,p,d,perm[d,k]] * W[d,k]  ==  sum_j x[b,p,d,j] * Wp[d,j]
// where Wp[d, perm[d,k]] = W[d,k]. So scatter W once into LDS and the x
// read becomes a perfectly contiguous stream (no gather).
//
// Each block: fixed channel d (blockIdx.x) + a chunk of (b,p) rows (blockIdx.y).
// Each of the 4 waves handles one (b,p) row per iteration:
//   lane i: f32x4 load x[row, d, 4i..4i+3], dot with register w4,
//   6-step shfl_xor 64-lane all-reduce, +bias, broadcast-store f32x4.
__global__ __launch_bounds__(256) void reuse_linear_kernel(
    const float* __restrict__ x,
    const float* __restrict__ W,
    const float* __restrict__ bias,
    const int*   __restrict__ perm,
    float*       __restrict__ out,
    int rows_per_block)
{
    __shared__ float wp[N_F];

    const int d     = blockIdx.x;       // channel
    const int chunk = blockIdx.y;       // row chunk
    const int tid   = threadIdx.x;      // 0..255

    // Scatter permuted weights into LDS (permutation => no write collisions).
    wp[perm[d * N_F + tid]] = W[d * N_F + tid];
    __syncthreads();

    const int lane = tid & 63;
    const int wave = tid >> 6;          // 0..3

    // Per-lane weight fragment is constant for this block: hoist to registers.
    const f32x4 w4 = *reinterpret_cast<const f32x4*>(&wp[lane * 4]);
    const float bv = bias[d];

    const int row0 = chunk * rows_per_block;
    for (int r = row0 + wave; r < row0 + rows_per_block; r += 4) {
        const size_t base = ((size_t)r * D_CH + d) * N_F;

        // Streaming (nontemporal) load: x is read exactly once, >L3 sized.
        const f32x4 x4 = __builtin_nontemporal_load(
            reinterpret_cast<const f32x4*>(x + base + lane * 4));
        float p = x4.x * w4.x + x4.y * w4.y + x4.z * w4.z + x4.w * w4.w;

        // 64-lane all-reduce (sum) via butterfly shuffles.
        #pragma unroll
        for (int m = 32; m >= 1; m >>= 1)
            p += __shfl_xor(p, m, 64);

        const float y = p + bv;
        f32x4 o;
        o.x = y; o.y = y; o.z = y; o.w = y;
        // Streaming store: out is written exactly once, never re-read.
        __builtin_nontemporal_store(o, reinterpret_cast<f32x4*>(out + base + lane * 4));
    }
}

extern "C" void kernel_launch(void* const* d_in, const int* in_sizes, int n_in,
                              void* d_out, int out_size, void* d_ws, size_t ws_size,
                              hipStream_t stream) {
    const float* x    = (const float*)d_in[0];
    const float* W    = (const float*)d_in[1];
    const float* bias = (const float*)d_in[2];
    const int*   perm = (const int*)d_in[3];
    float*       out  = (float*)d_out;

    // 16 chunks of 128 rows each; grid = 256 channels x 16 chunks = 4096 blocks.
    const int rows_per_block = ROWS_TOTAL / 16;   // 128
    dim3 grid(D_CH, 16);
    reuse_linear_kernel<<<grid, 256, 0, stream>>>(x, W, bias, perm, out, rows_per_block);
}

// Round 5
// 825.818 us; speedup vs baseline: 1.0132x; 1.0132x over previous
//
#include <hip/hip_runtime.h>

// Problem constants (B=16, P=128, D=256, N=256)
#define D_CH 256
#define N_F  256
#define ROWS_TOTAL 2048            // B*P (b,p) rows per channel d
#define CHUNKS 16
#define ROWS_PER_BLOCK (ROWS_TOTAL / CHUNKS)   // 128 (compile-time!)

// Native clang vector type — required by __builtin_nontemporal_load/store.
typedef float f32x4 __attribute__((ext_vector_type(4)));

// Algebra: perm is a permutation, so
//   sum_k x[b,p,d,perm[d,k]]*W[d,k] == sum_j x[b,p,d,j]*Wp[d,j],
//   Wp[d,perm[d,k]] = W[d,k]  -> scatter W into LDS once, stream x contiguously.
//
// ILP fix vs previous round: compile-time trip count + 2-row manual
// interleave + unroll 2 => >=4 independent global loads in flight per wave,
// shuffle chains from the two rows interleave in the DS pipe.
__global__ __launch_bounds__(256) void reuse_linear_kernel(
    const float* __restrict__ x,
    const float* __restrict__ W,
    const float* __restrict__ bias,
    const int*   __restrict__ perm,
    float*       __restrict__ out)
{
    __shared__ float wp[N_F];

    const int d     = blockIdx.x;       // channel
    const int chunk = blockIdx.y;       // row chunk
    const int tid   = threadIdx.x;      // 0..255

    // Scatter permuted weights into LDS (permutation => no collisions).
    wp[perm[d * N_F + tid]] = W[d * N_F + tid];
    __syncthreads();

    const int lane = tid & 63;
    const int wave = tid >> 6;          // 0..3

    const f32x4 w4 = *reinterpret_cast<const f32x4*>(&wp[lane * 4]);
    const float bv = bias[d];

    // Wave handles rows row0 + 4*i, i = 0..31 (two per loop body).
    const int row0 = chunk * ROWS_PER_BLOCK + wave;
    const size_t row_stride4 = (size_t)4 * D_CH * N_F;   // 4 rows apart

    #pragma unroll 2
    for (int i = 0; i < 32; i += 2) {
        const size_t b0 = ((size_t)(row0 + 4 * i) * D_CH + d) * N_F + lane * 4;
        const size_t b1 = b0 + row_stride4;

        // Both loads issue before either result is consumed.
        const f32x4 a0 = __builtin_nontemporal_load(
            reinterpret_cast<const f32x4*>(x + b0));
        const f32x4 a1 = __builtin_nontemporal_load(
            reinterpret_cast<const f32x4*>(x + b1));

        float p0 = a0.x * w4.x + a0.y * w4.y + a0.z * w4.z + a0.w * w4.w;
        float p1 = a1.x * w4.x + a1.y * w4.y + a1.z * w4.z + a1.w * w4.w;

        // Two interleaved 64-lane butterfly all-reduces.
        #pragma unroll
        for (int m = 32; m >= 1; m >>= 1) {
            p0 += __shfl_xor(p0, m, 64);
            p1 += __shfl_xor(p1, m, 64);
        }

        const float y0 = p0 + bv;
        const float y1 = p1 + bv;
        f32x4 o0; o0.x = o0.y = o0.z = o0.w = y0;
        f32x4 o1; o1.x = o1.y = o1.z = o1.w = y1;
        __builtin_nontemporal_store(o0, reinterpret_cast<f32x4*>(out + b0));
        __builtin_nontemporal_store(o1, reinterpret_cast<f32x4*>(out + b1));
    }
}

extern "C" void kernel_launch(void* const* d_in, const int* in_sizes, int n_in,
                              void* d_out, int out_size, void* d_ws, size_t ws_size,
                              hipStream_t stream) {
    const float* x    = (const float*)d_in[0];
    const float* W    = (const float*)d_in[1];
    const float* bias = (const float*)d_in[2];
    const int*   perm = (const int*)d_in[3];
    float*       out  = (float*)d_out;

    dim3 grid(D_CH, CHUNKS);   // 256 channels x 16 row-chunks = 4096 blocks
    reuse_linear_kernel<<<grid, 256, 0, stream>>>(x, W, bias, perm, out);
}